// Round 17
// baseline (172.442 us; speedup 1.0000x reference)
//
#include <hip/hip_runtime.h>
#include <hip/hip_bf16.h>
#include <stdint.h>

// B,C,H,W = 2,64,96,96. Inputs fp32, output fp32.
// proj3: QKV 1x1 convs -> bf16 q(*log2e), k, V key-permuted (bits 2<->3 of
//        key%32 swapped) channel-major.
// attn11: 32x32x16-MFMA flash attention. Wave = 32q x all keys of its
//         G-split; per 32-key tile: 1 QK MFMA + 2 ones-MFMA (lsum) + 4 PV
//         MFMA. E regs 0-7/8-15 are directly the two PV B-operand chunks
//         (V key-permuted). Zero LDS, zero syncthreads. Schraudolph bf16 P.
// combine: sum G key-split partials, normalize, + gamma*attn + x.
#define BB 2
#define CC 64
#define PP 9216
#define QTILES 144               // PP/64 (64 q per block = 2 waves x 32q)
#define LOG2E 1.4426950408889634f
// Schraudolph magic for bf16 2^E bits: E*128 + (127 - 0.05730496)*128
#define SCH_C 16248.664965f

typedef unsigned short ushort;
typedef __attribute__((ext_vector_type(8)))  short short8;
typedef __attribute__((ext_vector_type(4)))  float floatx4;
typedef __attribute__((ext_vector_type(16))) float floatx16;
typedef __attribute__((ext_vector_type(4)))  int intx4;

__device__ __forceinline__ ushort f2bf(float f) {
    unsigned int u = __float_as_uint(f);
    u = (u + 0x7fffu + ((u >> 16) & 1u)) >> 16;   // RNE
    return (ushort)u;
}

// 2^e0, 2^e1 as packed bf16 pair via Schraudolph (arg always > 0 -> trunc=floor)
__device__ __forceinline__ unsigned int exp2_pk_bf16(float e0, float e1) {
    const int i0 = (int)fmaf(e0, 128.f, SCH_C);
    const int i1 = (int)fmaf(e1, 128.f, SCH_C);
    return (unsigned int)i0 | ((unsigned int)i1 << 16);
}

// ---------------------------------------------------------------------------
// Kernel 1: QKV projection. 576 blocks x 256 (4 waves; wave = 64 px x 10 rows;
// 2 blocks per 64-px tile, each covering 40 of the 80 output rows).
// Rows 0-7: q (scaled by LOG2E), 8-15: k, 16-79: v.
// V keys permuted within 32-groups by SWAPPING BITS 2 AND 3 of key%32, so
// that QK's 32x32 D rows (row=(reg&3)+8*(reg>>2)+4*half) line up with PV's
// B-operand k-slots (k=half*8+j).
// ---------------------------------------------------------------------------
__global__ __launch_bounds__(256)
void proj3(const float* __restrict__ x,
           const float* __restrict__ Wq, const float* __restrict__ bq,
           const float* __restrict__ Wk, const float* __restrict__ bk,
           const float* __restrict__ Wv, const float* __restrict__ bv,
           ushort* __restrict__ qbuf, ushort* __restrict__ kbuf,
           ushort* __restrict__ vfw)
{
    const int tid = threadIdx.x;
    const int px  = tid & 63;
    const int og  = __builtin_amdgcn_readfirstlane(tid >> 6);  // 0..3, wave-uniform
    const int blk = blockIdx.x;
    const int b     = blk / (2 * QTILES);
    const int rem   = blk % (2 * QTILES);
    const int ptile = rem >> 1;
    const int rhalf = rem & 1;
    const int p     = ptile * 64 + px;
    const int r0    = rhalf * 40 + og * 10;      // first of this thread's 10 rows

    const float* wr[10];
#pragma unroll
    for (int r = 0; r < 10; ++r) {
        const int row = r0 + r;
        wr[r] = (row < 8) ? (Wq + row * 64)
              : (row < 16) ? (Wk + (row - 8) * 64)
              : (Wv + (row - 16) * 64);
    }

    float xv[64];
#pragma unroll
    for (int c = 0; c < 64; ++c)
        xv[c] = x[((size_t)b * 64 + c) * PP + p];

    float acc[10];
#pragma unroll
    for (int r = 0; r < 10; ++r) acc[r] = 0.f;
#pragma unroll
    for (int c = 0; c < 64; ++c) {
#pragma unroll
        for (int r = 0; r < 10; ++r)
            acc[r] = fmaf(wr[r][c], xv[c], acc[r]);
    }

#pragma unroll
    for (int r = 0; r < 10; ++r) {
        const int row = r0 + r;
        if (row < 8) {
            const float v = (acc[r] + bq[row]) * LOG2E;
            qbuf[((size_t)b * PP + p) * 8 + row] = f2bf(v);
        } else if (row < 16) {
            const float v = acc[r] + bk[row - 8];
            kbuf[((size_t)b * PP + p) * 8 + (row - 8)] = f2bf(v);
        } else {
            const int co = row - 16;
            const float v = acc[r] + bv[co];
            const int pl = p & 31;     // swap bits 2 and 3 of key%32
            const int ps = (p & ~31) | (pl & 0x13) | ((pl & 4) << 1) | ((pl & 8) >> 1);
            vfw[((size_t)b * 64 + co) * PP + ps] = f2bf(v);
        }
    }
}

// One 32-key tile: QK (A=K, B=Q) -> Schraudolph bf16 P (regs 0-7 / 8-15 are
// the two PV chunks) -> ones-MFMA lsum -> 4 PV MFMAs. All indices literal.
#define COMPUTE_TILE32(KF, Vc0b0, Vc0b1, Vc1b0, Vc1b1)                         \
    {                                                                          \
        const floatx16 E = __builtin_amdgcn_mfma_f32_32x32x16_bf16(            \
            KF, qf, zero16, 0, 0, 0);                                          \
        intx4 pi0, pi1;                                                        \
        pi0.x = (int)exp2_pk_bf16(E[0],  E[1]);                                \
        pi0.y = (int)exp2_pk_bf16(E[2],  E[3]);                                \
        pi0.z = (int)exp2_pk_bf16(E[4],  E[5]);                                \
        pi0.w = (int)exp2_pk_bf16(E[6],  E[7]);                                \
        pi1.x = (int)exp2_pk_bf16(E[8],  E[9]);                                \
        pi1.y = (int)exp2_pk_bf16(E[10], E[11]);                               \
        pi1.z = (int)exp2_pk_bf16(E[12], E[13]);                               \
        pi1.w = (int)exp2_pk_bf16(E[14], E[15]);                               \
        const short8 pf0 = __builtin_bit_cast(short8, pi0);                    \
        const short8 pf1 = __builtin_bit_cast(short8, pi1);                    \
        accL = __builtin_amdgcn_mfma_f32_32x32x16_bf16(vones, pf0, accL, 0, 0, 0); \
        accL = __builtin_amdgcn_mfma_f32_32x32x16_bf16(vones, pf1, accL, 0, 0, 0); \
        acc0 = __builtin_amdgcn_mfma_f32_32x32x16_bf16(Vc0b0, pf0, acc0, 0, 0, 0); \
        acc1 = __builtin_amdgcn_mfma_f32_32x32x16_bf16(Vc0b1, pf0, acc1, 0, 0, 0); \
        acc0 = __builtin_amdgcn_mfma_f32_32x32x16_bf16(Vc1b0, pf1, acc0, 0, 0, 0); \
        acc1 = __builtin_amdgcn_mfma_f32_32x32x16_bf16(Vc1b1, pf1, acc1, 0, 0, 0); \
    }

// ---------------------------------------------------------------------------
// Kernel 2: 32x32-MFMA flash attention. Grid = G*BB*QTILES blocks of 128
// (2 independent waves; wave = 32 q x keysPerG keys). No LDS, no barriers.
// QK: E = mfma_32x32x16(A=K, B=Q) -> D[key][q]; Q k-slots 8-15 zeroed so
// K's half-1 d-slots (garbage) contribute 0. V key-permuted to slot order.
// lsum via ones-A MFMA (all D rows equal the per-q key-sum).
// ---------------------------------------------------------------------------
__global__ __launch_bounds__(128, 3)
void attn11(const ushort* __restrict__ qbuf, const ushort* __restrict__ kbuf,
            const ushort* __restrict__ vfw,
            ushort* __restrict__ accp, float* __restrict__ lsump,
            int keysPerG, int numTiles)
{
    const int tid  = threadIdx.x;
    const int lane = tid & 63;
    const int wid  = tid >> 6;
    const int l31  = lane & 31;
    const int hf   = lane >> 5;          // 0/1

    const int qt = blockIdx.x % QTILES;
    const int gb = blockIdx.x / QTILES;
    const int b  = gb % BB;
    const int g  = gb / BB;
    const int q0 = qt * 64 + wid * 32;   // this wave's 32 queries

    const short8 zf = {0, 0, 0, 0, 0, 0, 0, 0};
    const short vone = (short)0x3F80;    // bf16 1.0
    const short8 vones = {vone, vone, vone, vone, vone, vone, vone, vone};
    const floatx16 zero16 = {0.f, 0.f, 0.f, 0.f, 0.f, 0.f, 0.f, 0.f,
                             0.f, 0.f, 0.f, 0.f, 0.f, 0.f, 0.f, 0.f};

    // Q B-frag: B[k=hf*8+j][n=q=l31]; half 1 (d 8-15) zero.
    const short8 qf = (hf == 0)
        ? *(const short8*)(qbuf + ((size_t)b * PP + q0 + l31) * 8)
        : zf;

    floatx16 acc0 = zero16;   // channels 0-31
    floatx16 acc1 = zero16;   // channels 32-63
    floatx16 accL = zero16;   // lsum (all rows equal)

    const ushort* kB = kbuf + (size_t)b * PP * 8;
    const ushort* vB = vfw + (size_t)b * 64 * PP;
    const int kwbase = g * keysPerG;

    // ---- prologue: tile 0 fragments (named scalars only) ----
    // K A-frag: A[m=key=l31][k]; both halves load the real d0-7 row (half-1
    // slots are multiplied by Q's zeros).
    short8 kfa = *(const short8*)(kB + (size_t)(kwbase + l31) * 8);
    short8 va00 = *(const short8*)(vB + ((size_t)(0 * 32 + l31)) * PP + kwbase + 0 * 16 + hf * 8);
    short8 va01 = *(const short8*)(vB + ((size_t)(1 * 32 + l31)) * PP + kwbase + 0 * 16 + hf * 8);
    short8 va10 = *(const short8*)(vB + ((size_t)(0 * 32 + l31)) * PP + kwbase + 1 * 16 + hf * 8);
    short8 va11 = *(const short8*)(vB + ((size_t)(1 * 32 + l31)) * PP + kwbase + 1 * 16 + hf * 8);

    // numTiles = keysPerG/32 is even for every G in the ladder (36/48/72/144)
    for (int t = 0; t < numTiles; t += 2) {
        // -- half A: prefetch tile t+1 into B set, compute tile t --
        const int kw1 = kwbase + (t + 1) * 32;
        const short8 kfb  = *(const short8*)(kB + (size_t)(kw1 + l31) * 8);
        const short8 vb00 = *(const short8*)(vB + ((size_t)(0 * 32 + l31)) * PP + kw1 + 0 * 16 + hf * 8);
        const short8 vb01 = *(const short8*)(vB + ((size_t)(1 * 32 + l31)) * PP + kw1 + 0 * 16 + hf * 8);
        const short8 vb10 = *(const short8*)(vB + ((size_t)(0 * 32 + l31)) * PP + kw1 + 1 * 16 + hf * 8);
        const short8 vb11 = *(const short8*)(vB + ((size_t)(1 * 32 + l31)) * PP + kw1 + 1 * 16 + hf * 8);

        COMPUTE_TILE32(kfa, va00, va01, va10, va11)

        // -- half B: prefetch tile t+2 into A set, compute tile t+1 --
        const int kw2 = (t + 2 < numTiles) ? (kwbase + (t + 2) * 32) : kw1;
        kfa  = *(const short8*)(kB + (size_t)(kw2 + l31) * 8);
        va00 = *(const short8*)(vB + ((size_t)(0 * 32 + l31)) * PP + kw2 + 0 * 16 + hf * 8);
        va01 = *(const short8*)(vB + ((size_t)(1 * 32 + l31)) * PP + kw2 + 0 * 16 + hf * 8);
        va10 = *(const short8*)(vB + ((size_t)(0 * 32 + l31)) * PP + kw2 + 1 * 16 + hf * 8);
        va11 = *(const short8*)(vB + ((size_t)(1 * 32 + l31)) * PP + kw2 + 1 * 16 + hf * 8);

        COMPUTE_TILE32(kfb, vb00, vb01, vb10, vb11)
    }

    // ---- epilogue: direct stores, no cross-wave traffic ----
    // D row (channel within block) = (r&3) + 8*(r>>2) + 4*hf; q = q0 + l31.
    ushort* ab = accp + ((size_t)g * BB + b) * CC * PP;
#pragma unroll
    for (int r = 0; r < 16; ++r) {
        const int row = (r & 3) + 8 * (r >> 2) + 4 * hf;
        ab[(size_t)row * PP + q0 + l31]        = f2bf(acc0[r]);
        ab[(size_t)(32 + row) * PP + q0 + l31] = f2bf(acc1[r]);
    }
    if (lane < 32)
        lsump[((size_t)g * BB + b) * PP + q0 + lane] = accL[0];
}

// ---------------------------------------------------------------------------
// Kernel 3: combine G partials, normalize, + gamma*attn + x. 576 x 256,
// 8 consecutive pixels per thread (layouts already [b][c][p]-major).
// ---------------------------------------------------------------------------
__global__ __launch_bounds__(256)
void combine(const ushort* __restrict__ accp, const float* __restrict__ lsump,
             const float* __restrict__ x, const float* __restrict__ gamma,
             float* __restrict__ out, int G)
{
    const size_t i8 = ((size_t)blockIdx.x * 256 + threadIdx.x) * 8;
    const int b = (int)(i8 / ((size_t)CC * PP));
    const int p = (int)(i8 % PP);
    const float gm = gamma[0];

    float asum[8] = {}, lst[8] = {};
    for (int g = 0; g < G; ++g) {
        const uint4 av = *(const uint4*)(accp + (size_t)g * (BB * CC * PP) + i8);
        const unsigned int u[4] = {av.x, av.y, av.z, av.w};
#pragma unroll
        for (int k = 0; k < 4; ++k) {
            asum[2 * k]     += __uint_as_float(u[k] << 16);
            asum[2 * k + 1] += __uint_as_float(u[k] & 0xffff0000u);
        }
        const float* lp = lsump + ((size_t)g * BB + b) * PP + p;
        const float4 l0 = *(const float4*)lp;
        const float4 l1 = *(const float4*)(lp + 4);
        lst[0] += l0.x; lst[1] += l0.y; lst[2] += l0.z; lst[3] += l0.w;
        lst[4] += l1.x; lst[5] += l1.y; lst[6] += l1.z; lst[7] += l1.w;
    }

    const float4 x0 = *(const float4*)(x + i8);
    const float4 x1 = *(const float4*)(x + i8 + 4);
    float o[8] = {x0.x, x0.y, x0.z, x0.w, x1.x, x1.y, x1.z, x1.w};
#pragma unroll
    for (int j = 0; j < 8; ++j)
        o[j] = fmaf(asum[j], gm / fmaxf(lst[j], 1e-30f), o[j]);
    *(float4*)(out + i8)     = make_float4(o[0], o[1], o[2], o[3]);
    *(float4*)(out + i8 + 4) = make_float4(o[4], o[5], o[6], o[7]);
}

// ---------------------------------------------------------------------------
extern "C" void kernel_launch(void* const* d_in, const int* in_sizes, int n_in,
                              void* d_out, int out_size, void* d_ws, size_t ws_size,
                              hipStream_t stream)
{
    const float* x     = (const float*)d_in[0];
    const float* Wq    = (const float*)d_in[1];
    const float* bq    = (const float*)d_in[2];
    const float* Wk    = (const float*)d_in[3];
    const float* bk    = (const float*)d_in[4];
    const float* Wv    = (const float*)d_in[5];
    const float* bv    = (const float*)d_in[6];
    const float* gamma = (const float*)d_in[7];
    float* out = (float*)d_out;

    // ws: qbuf | kbuf | vfw (bf16) | accp (bf16, G slots) | lsump (f32)
    const size_t nQK  = (size_t)BB * PP * 8;        // elems
    const size_t nV   = (size_t)BB * CC * PP;
    const size_t base = 2 * nQK * 2 + nV * 2;       // bytes
    const size_t perG = nV * 2 + (size_t)BB * PP * 4;
    const int G = (ws_size >= base + 8 * perG) ? 8
                : (ws_size >= base + 6 * perG) ? 6
                : (ws_size >= base + 4 * perG) ? 4 : 2;
    const int keysPerG = PP / G;
    const int numTiles = keysPerG / 32;             // even for all G above

    ushort* qbuf = (ushort*)d_ws;
    ushort* kbuf = qbuf + nQK;
    ushort* vfw  = kbuf + nQK;
    ushort* accp = vfw + nV;
    float* lsump = (float*)(accp + (size_t)G * nV);

    proj3<<<dim3(BB * 2 * QTILES), dim3(256), 0, stream>>>(
        x, Wq, bq, Wk, bk, Wv, bv, qbuf, kbuf, vfw);
    attn11<<<dim3(G * BB * QTILES), dim3(128), 0, stream>>>(
        qbuf, kbuf, vfw, accp, lsump, keysPerG, numTiles);
    combine<<<dim3(576), dim3(256), 0, stream>>>(
        accp, lsump, x, gamma, out, G);
}